// Round 14
// baseline (553.063 us; speedup 1.0000x reference)
//
#include <hip/hip_runtime.h>
#include <stdint.h>

#define T_STEPS 32
#define DECAY   0.951229424500714f    // exp(-1/20)
#define DECAY16 0.449328964117222f    // exp(-16/20)

typedef __attribute__((ext_vector_type(4))) float f32x4;
typedef __attribute__((ext_vector_type(8))) short bf16x8;
typedef __attribute__((ext_vector_type(4))) unsigned short u16x4;   // native vec for nt-store

typedef const void __attribute__((address_space(1)))* gptr_t;
typedef void __attribute__((address_space(3)))* sptr_t;

__device__ __forceinline__ unsigned short f2bf(float f) {
    unsigned u = __builtin_bit_cast(unsigned, f);
    return (unsigned short)((u + 0x7FFFu + ((u >> 16) & 1u)) >> 16);
}

// Fused producer-consumer kernel.
//   blocks [0, 512): GEMM role (convert own W slice -> spin on band -> GEMM)
//   blocks [512, 4608): prep role (one row of temporal reduce -> release band ctr)
// Capacity: 48 KiB LDS -> 3 blocks/CU = 768 slots; 512 spinners always leave
// >=256 slots for prep -> deadlock-free under any dispatch order.
// Cross-block data (mem, Wb) written with NT stores (lands past L2);
// producer release-atomic / consumer acquire-load per guide §6 G16.
#define BM 64
#define BN 128
#define BK 32
#define GEMM_BLOCKS 512      // (4096/64) * (1024/128)
#define NROW 4096
#define NCOL 1024            // K = Din
#define NOUT 1024            // N = Dout

__global__ __launch_bounds__(256) void fused_kernel(
    const float* __restrict__ x, const float* __restrict__ W,
    const float* __restrict__ bias, float* __restrict__ C,
    unsigned short* __restrict__ mem, unsigned short* __restrict__ Wb,
    unsigned* __restrict__ bandCnt, unsigned* __restrict__ wCnt)
{
    __shared__ unsigned short As[4][BM][BK];   // 4 x 4 KiB
    __shared__ unsigned short Bs[4][BN][BK];   // 4 x 8 KiB   (48 KiB total)

    int tid  = threadIdx.x;

    if ((int)blockIdx.x >= GEMM_BLOCKS) {
        // ---------------- prep role: one row ----------------
        int row = (int)blockIdx.x - GEMM_BLOCKS;           // 0..4095
        const f32x4* xr = (const f32x4*)(x + (size_t)row * T_STEPS * NCOL) + tid;
        f32x4 accH = {0.f,0.f,0.f,0.f};
        f32x4 accL = {0.f,0.f,0.f,0.f};
        #pragma unroll
        for (int t = 0; t < 16; ++t) {
            f32x4 vh = __builtin_nontemporal_load(&xr[(size_t)t * 256]);
            f32x4 vl = __builtin_nontemporal_load(&xr[(size_t)(t + 16) * 256]);
            accH = accH * DECAY + vh;
            accL = accL * DECAY + vl;
        }
        f32x4 a = accH * DECAY16 + accL;
        u16x4 o = { f2bf(a.x), f2bf(a.y), f2bf(a.z), f2bf(a.w) };
        __builtin_nontemporal_store(o, (u16x4*)(mem + (size_t)row * NCOL + tid * 4));
        __syncthreads();   // all stores acked (compiler emits vmcnt(0) pre-barrier)
        if (tid == 0)
            __hip_atomic_fetch_add(&bandCnt[row >> 6], 1u,
                                   __ATOMIC_RELEASE, __HIP_MEMORY_SCOPE_AGENT);
        return;
    }

    // ---------------- GEMM role ----------------
    int g  = (int)blockIdx.x;
    int bm = g >> 3;             // band (64 rows)
    int bn = g & 7;              // 128-col panel

    // convert this block's W slice fp32->bf16 (512 f32x4 per block, nt stores)
    {
        const f32x4* Wv = (const f32x4*)W;
        #pragma unroll
        for (int j = 0; j < 2; ++j) {
            int idx = g * 512 + j * 256 + tid;
            f32x4 v = Wv[idx];
            u16x4 o = { f2bf(v.x), f2bf(v.y), f2bf(v.z), f2bf(v.w) };
            __builtin_nontemporal_store(o, (u16x4*)(Wb + (size_t)idx * 4));
        }
    }
    __syncthreads();
    if (tid == 0) {
        __hip_atomic_fetch_add(wCnt, 1u, __ATOMIC_RELEASE, __HIP_MEMORY_SCOPE_AGENT);
        while (__hip_atomic_load(&bandCnt[bm], __ATOMIC_RELAXED,
                                 __HIP_MEMORY_SCOPE_AGENT) < 64u)
            __builtin_amdgcn_s_sleep(8);
        while (__hip_atomic_load(wCnt, __ATOMIC_RELAXED,
                                 __HIP_MEMORY_SCOPE_AGENT) < (unsigned)GEMM_BLOCKS)
            __builtin_amdgcn_s_sleep(8);
        (void)__hip_atomic_load(wCnt, __ATOMIC_ACQUIRE, __HIP_MEMORY_SCOPE_AGENT);
    }
    __syncthreads();

    // ---- R9 GEMM body: 64x128 tile, chunk-swizzled LDS, depth-3, vmcnt(6) ----
    int lane = tid & 63;
    int wid  = tid >> 6;
    int wr   = wid >> 1;
    int wc   = wid & 1;

    int srow    = tid >> 2;
    int swchunk = (tid & 3) ^ ((srow >> 1) & 3);
    int swcol   = swchunk << 3;

    const unsigned short* Ag  = mem + (size_t)(bm * BM + srow) * NCOL + swcol;
    const unsigned short* Bg0 = Wb  + (size_t)(bn * BN + srow) * NCOL + swcol;
    const unsigned short* Bg1 = Wb  + (size_t)(bn * BN + 64 + srow) * NCOL + swcol;

    f32x4 acc[2][4] = {};

    int fr = lane & 15;
    int swoff = (((lane >> 4) ^ ((fr >> 1) & 3)) << 4);

    auto stage = [&](int b, int kt) {
        int k0 = kt * BK;
        __builtin_amdgcn_global_load_lds((gptr_t)(Ag  + k0), (sptr_t)(&As[b][srow][(tid & 3) << 3]),      16, 0, 0);
        __builtin_amdgcn_global_load_lds((gptr_t)(Bg0 + k0), (sptr_t)(&Bs[b][srow][(tid & 3) << 3]),      16, 0, 0);
        __builtin_amdgcn_global_load_lds((gptr_t)(Bg1 + k0), (sptr_t)(&Bs[b][64 + srow][(tid & 3) << 3]), 16, 0, 0);
    };

    int nk = NCOL / BK;          // 32

    stage(0, 0);
    stage(1, 1);
    stage(2, 2);                                       // 9 loads outstanding
    asm volatile("s_waitcnt vmcnt(6)" ::: "memory");   // buf0 landed
    __builtin_amdgcn_s_barrier();

    for (int kt = 0; kt < nk; ++kt) {
        int cur = kt & 3;
        if (kt + 3 < nk) stage((kt + 3) & 3, kt + 3);

        const char* Ab = (const char*)&As[cur][0][0];
        const char* Bb = (const char*)&Bs[cur][0][0];
        bf16x8 a0 = *(const bf16x8*)(Ab + (wr * 32 +      fr) * 64 + swoff);
        bf16x8 a1 = *(const bf16x8*)(Ab + (wr * 32 + 16 + fr) * 64 + swoff);
        bf16x8 b0 = *(const bf16x8*)(Bb + (wc * 64 +      fr) * 64 + swoff);
        bf16x8 b1 = *(const bf16x8*)(Bb + (wc * 64 + 16 + fr) * 64 + swoff);
        bf16x8 b2 = *(const bf16x8*)(Bb + (wc * 64 + 32 + fr) * 64 + swoff);
        bf16x8 b3 = *(const bf16x8*)(Bb + (wc * 64 + 48 + fr) * 64 + swoff);

        acc[0][0] = __builtin_amdgcn_mfma_f32_16x16x32_bf16(a0, b0, acc[0][0], 0, 0, 0);
        acc[0][1] = __builtin_amdgcn_mfma_f32_16x16x32_bf16(a0, b1, acc[0][1], 0, 0, 0);
        acc[0][2] = __builtin_amdgcn_mfma_f32_16x16x32_bf16(a0, b2, acc[0][2], 0, 0, 0);
        acc[0][3] = __builtin_amdgcn_mfma_f32_16x16x32_bf16(a0, b3, acc[0][3], 0, 0, 0);
        acc[1][0] = __builtin_amdgcn_mfma_f32_16x16x32_bf16(a1, b0, acc[1][0], 0, 0, 0);
        acc[1][1] = __builtin_amdgcn_mfma_f32_16x16x32_bf16(a1, b1, acc[1][1], 0, 0, 0);
        acc[1][2] = __builtin_amdgcn_mfma_f32_16x16x32_bf16(a1, b2, acc[1][2], 0, 0, 0);
        acc[1][3] = __builtin_amdgcn_mfma_f32_16x16x32_bf16(a1, b3, acc[1][3], 0, 0, 0);

        if (kt + 3 < nk) {
            asm volatile("s_waitcnt vmcnt(6)" ::: "memory");
        } else if (kt + 2 < nk) {
            asm volatile("s_waitcnt vmcnt(3)" ::: "memory");
        } else if (kt + 1 < nk) {
            asm volatile("s_waitcnt vmcnt(0)" ::: "memory");
        }
        if (kt + 1 < nk) __builtin_amdgcn_s_barrier();
    }

    int fc  = lane & 15;
    int fq  = (lane >> 4) << 2;
    int row0 = bm * BM + wr * 32;
    int col0 = bn * BN + wc * 64;
    #pragma unroll
    for (int mi = 0; mi < 2; ++mi) {
        #pragma unroll
        for (int ni = 0; ni < 4; ++ni) {
            int col = col0 + ni * 16 + fc;
            float bv = bias[col];
            #pragma unroll
            for (int r = 0; r < 4; ++r) {
                int row = row0 + mi * 16 + fq + r;
                __builtin_nontemporal_store(acc[mi][ni][r] + bv, &C[(size_t)row * NOUT + col]);
            }
        }
    }
}

extern "C" void kernel_launch(void* const* d_in, const int* in_sizes, int n_in,
                              void* d_out, int out_size, void* d_ws, size_t ws_size,
                              hipStream_t stream) {
    const float* x    = (const float*)d_in[0];
    const float* W    = (const float*)d_in[1];
    const float* bias = (const float*)d_in[2];
    float* out = (float*)d_out;

    // ws layout: mem bf16 [8 MiB] | Wb bf16 [2 MiB] | counters [512 B]
    unsigned short* mem = (unsigned short*)d_ws;
    unsigned short* Wb  = (unsigned short*)d_ws + (size_t)NROW * NCOL;
    unsigned* ctr = (unsigned*)((char*)d_ws + (size_t)(NROW + NOUT) * NCOL * 2);
    unsigned* bandCnt = ctr;          // 64 bands
    unsigned* wCnt    = ctr + 64;

    (void)hipMemsetAsync(ctr, 0, 512, stream);

    fused_kernel<<<GEMM_BLOCKS + NROW, 256, 0, stream>>>(
        x, W, bias, out, mem, Wb, bandCnt, wCnt);
}

// Round 15
// 112.923 us; speedup vs baseline: 4.8977x; 4.8977x over previous
//
#include <hip/hip_runtime.h>
#include <stdint.h>

#define T_STEPS 32
#define DECAY   0.951229424500714f    // exp(-1/20)
#define DECAY16 0.449328964117222f    // exp(-16/20)

typedef __attribute__((ext_vector_type(4))) float f32x4;
typedef __attribute__((ext_vector_type(8))) short bf16x8;

typedef const void __attribute__((address_space(1)))* gptr_t;
typedef void __attribute__((address_space(3)))* sptr_t;

__device__ __forceinline__ unsigned short f2bf(float f) {
    unsigned u = __builtin_bit_cast(unsigned, f);
    return (unsigned short)((u + 0x7FFFu + ((u >> 16) & 1u)) >> 16);
}

// blocks [0, mBlocks): temporal leaky reduce, TWO rows per block ->
//   4 independent FMA chains per thread (2x memory-level parallelism vs R12).
// blocks [mBlocks, ...): convert W fp32 -> bf16.
// nt loads on the x stream are PROTECTED (removing them cost ~10 µs, R11).
__global__ __launch_bounds__(256) void prep_kernel(
    const float* __restrict__ x, const float* __restrict__ W,
    unsigned short* __restrict__ mem, unsigned short* __restrict__ Wb,
    int mBlocks, int M, int D)
{
    int tid = threadIdx.x;
    if ((int)blockIdx.x < mBlocks) {
        int row0 = blockIdx.x * 2;                 // two rows per block
        size_t rowstr4 = (size_t)T_STEPS * D / 4;  // f32x4 row stride
        const f32x4* xr0 = (const f32x4*)(x + (size_t)row0 * T_STEPS * D) + tid;
        const f32x4* xr1 = xr0 + rowstr4;
        int perRow = D >> 2;                       // f32x4 per row (=256)

        f32x4 h0 = {0.f,0.f,0.f,0.f}, l0 = {0.f,0.f,0.f,0.f};
        f32x4 h1 = {0.f,0.f,0.f,0.f}, l1 = {0.f,0.f,0.f,0.f};
        #pragma unroll
        for (int t = 0; t < 16; ++t) {             // 4 independent chains
            f32x4 a = __builtin_nontemporal_load(&xr0[(size_t)t * perRow]);
            f32x4 b = __builtin_nontemporal_load(&xr0[(size_t)(t + 16) * perRow]);
            f32x4 c = __builtin_nontemporal_load(&xr1[(size_t)t * perRow]);
            f32x4 d = __builtin_nontemporal_load(&xr1[(size_t)(t + 16) * perRow]);
            h0 = h0 * DECAY + a;  l0 = l0 * DECAY + b;
            h1 = h1 * DECAY + c;  l1 = l1 * DECAY + d;
        }
        f32x4 r0 = h0 * DECAY16 + l0;
        f32x4 r1 = h1 * DECAY16 + l1;
        ushort4 o0, o1;
        o0.x = f2bf(r0.x); o0.y = f2bf(r0.y); o0.z = f2bf(r0.z); o0.w = f2bf(r0.w);
        o1.x = f2bf(r1.x); o1.y = f2bf(r1.y); o1.z = f2bf(r1.z); o1.w = f2bf(r1.w);
        *(ushort4*)(mem + (size_t)row0 * D + tid * 4)       = o0;
        *(ushort4*)(mem + (size_t)(row0 + 1) * D + tid * 4) = o1;
    } else {
        int idx = (blockIdx.x - mBlocks) * 256 + tid;
        f32x4 v = ((const f32x4*)W)[idx];
        ushort4 o;
        o.x = f2bf(v.x); o.y = f2bf(v.y); o.z = f2bf(v.z); o.w = f2bf(v.w);
        *(ushort4*)(Wb + (size_t)idx * 4) = o;
    }
}

// C[M][N] = A[M][K] @ B[N][K]^T + bias, bf16 inputs, fp32 out
// (byte-identical to R12 champion: 64x128 tile, pair-step K-loop, 6 LDS
//  buffers, one barrier + one counted vmcnt per TWO K-steps, chunk swizzle)
#define BM 64
#define BN 128
#define BK 32
#define NBUF 6

__global__ __launch_bounds__(256) void gemm_kernel(
    const unsigned short* __restrict__ A,    // mem bf16 [M][K]
    const unsigned short* __restrict__ Bw,   // W bf16 [N][K]
    const float* __restrict__ bias,          // [N]
    float* __restrict__ C,                   // [M][N]
    int M, int N, int K)
{
    __shared__ unsigned short As[NBUF][BM][BK];   // 6 x 4 KiB
    __shared__ unsigned short Bs[NBUF][BN][BK];   // 6 x 8 KiB  (72 KiB total)

    // XCD-aware swizzle (grid=512, 512%8==0 -> bijective)
    int nwg = gridDim.x;
    int cpx = nwg >> 3;
    int bid = (int)blockIdx.x;
    int wg  = (bid & 7) * cpx + (bid >> 3);

    int nbn = N / BN;
    int bm = wg / nbn;
    int bn = wg % nbn;

    int tid  = threadIdx.x;
    int lane = tid & 63;
    int wid  = tid >> 6;         // 0..3
    int wr   = wid >> 1;         // wave row block (32 rows)
    int wc   = wid & 1;          // wave col block (64 cols)

    // staging: LDS dest byte = 16*tid (linear). Global source col swizzled:
    // thread covers (srow, chunk=tid&3); source chunk = chunk ^ ((srow>>1)&3).
    int srow    = tid >> 2;                              // 0..63
    int swchunk = (tid & 3) ^ ((srow >> 1) & 3);
    int swcol   = swchunk << 3;                          // bf16 units

    const unsigned short* Ag  = A  + (size_t)(bm * BM + srow) * K + swcol;
    const unsigned short* Bg0 = Bw + (size_t)(bn * BN + srow) * K + swcol;
    const unsigned short* Bg1 = Bw + (size_t)(bn * BN + 64 + srow) * K + swcol;
    // (64+srow)>>1 & 3 == (srow>>1)&3 since 32%4==0 — swizzle class consistent.

    f32x4 acc[2][4] = {};

    int fr = lane & 15;          // row within 16x16 fragment
    // swizzled lane-constant 16B offset: chunk c=lane>>4, XOR (fr>>1)&3
    int swoff = (((lane >> 4) ^ ((fr >> 1) & 3)) << 4);  // bytes

    auto stage = [&](int b, int kt) {
        int k0 = kt * BK;
        __builtin_amdgcn_global_load_lds((gptr_t)(Ag  + k0), (sptr_t)(&As[b][srow][(tid & 3) << 3]),      16, 0, 0);
        __builtin_amdgcn_global_load_lds((gptr_t)(Bg0 + k0), (sptr_t)(&Bs[b][srow][(tid & 3) << 3]),      16, 0, 0);
        __builtin_amdgcn_global_load_lds((gptr_t)(Bg1 + k0), (sptr_t)(&Bs[b][64 + srow][(tid & 3) << 3]), 16, 0, 0);
    };

    auto compute = [&](int b) {
        const char* Ab = (const char*)&As[b][0][0];
        const char* Bb = (const char*)&Bs[b][0][0];
        bf16x8 a0 = *(const bf16x8*)(Ab + (wr * 32 +      fr) * 64 + swoff);
        bf16x8 a1 = *(const bf16x8*)(Ab + (wr * 32 + 16 + fr) * 64 + swoff);
        bf16x8 b0 = *(const bf16x8*)(Bb + (wc * 64 +      fr) * 64 + swoff);
        bf16x8 b1 = *(const bf16x8*)(Bb + (wc * 64 + 16 + fr) * 64 + swoff);
        bf16x8 b2 = *(const bf16x8*)(Bb + (wc * 64 + 32 + fr) * 64 + swoff);
        bf16x8 b3 = *(const bf16x8*)(Bb + (wc * 64 + 48 + fr) * 64 + swoff);

        acc[0][0] = __builtin_amdgcn_mfma_f32_16x16x32_bf16(a0, b0, acc[0][0], 0, 0, 0);
        acc[0][1] = __builtin_amdgcn_mfma_f32_16x16x32_bf16(a0, b1, acc[0][1], 0, 0, 0);
        acc[0][2] = __builtin_amdgcn_mfma_f32_16x16x32_bf16(a0, b2, acc[0][2], 0, 0, 0);
        acc[0][3] = __builtin_amdgcn_mfma_f32_16x16x32_bf16(a0, b3, acc[0][3], 0, 0, 0);
        acc[1][0] = __builtin_amdgcn_mfma_f32_16x16x32_bf16(a1, b0, acc[1][0], 0, 0, 0);
        acc[1][1] = __builtin_amdgcn_mfma_f32_16x16x32_bf16(a1, b1, acc[1][1], 0, 0, 0);
        acc[1][2] = __builtin_amdgcn_mfma_f32_16x16x32_bf16(a1, b2, acc[1][2], 0, 0, 0);
        acc[1][3] = __builtin_amdgcn_mfma_f32_16x16x32_bf16(a1, b3, acc[1][3], 0, 0, 0);
    };

    int nk = K / BK;             // 32 (even)

    stage(0, 0);
    stage(1, 1);
    stage(2, 2);
    stage(3, 3);                 // 12 loads outstanding

    for (int kt = 0; kt < nk; kt += 2) {
        // stages kt,kt+1 landed; kt+2,kt+3 still in flight (never drain mid-loop)
        if (kt + 2 < nk) {
            asm volatile("s_waitcnt vmcnt(6)" ::: "memory");
        } else {
            asm volatile("s_waitcnt vmcnt(0)" ::: "memory");
        }
        // one barrier per pair: all waves past compute(kt-2),(kt-1) — so
        // staging bufs (kt+4)%6,(kt+5)%6 (last read at kt-2,kt-1) is safe.
        __builtin_amdgcn_s_barrier();

        if (kt + 4 < nk) stage((kt + 4) % NBUF, kt + 4);
        if (kt + 5 < nk) stage((kt + 5) % NBUF, kt + 5);

        compute(kt % NBUF);
        compute((kt + 1) % NBUF);
    }

    // C/D layout: col = lane&15, row = (lane>>4)*4 + reg
    int fc  = lane & 15;
    int fq  = (lane >> 4) << 2;
    int row0 = bm * BM + wr * 32;
    int col0 = bn * BN + wc * 64;
    #pragma unroll
    for (int mi = 0; mi < 2; ++mi) {
        #pragma unroll
        for (int ni = 0; ni < 4; ++ni) {
            int col = col0 + ni * 16 + fc;
            float bv = bias[col];
            #pragma unroll
            for (int r = 0; r < 4; ++r) {
                int row = row0 + mi * 16 + fq + r;
                __builtin_nontemporal_store(acc[mi][ni][r] + bv, &C[(size_t)row * N + col]);
            }
        }
    }
}

extern "C" void kernel_launch(void* const* d_in, const int* in_sizes, int n_in,
                              void* d_out, int out_size, void* d_ws, size_t ws_size,
                              hipStream_t stream) {
    const float* x    = (const float*)d_in[0];
    const float* W    = (const float*)d_in[1];
    const float* bias = (const float*)d_in[2];
    float* out = (float*)d_out;

    int Dout = in_sizes[2];                   // 1024
    int Din  = in_sizes[1] / Dout;            // 1024
    int M    = in_sizes[0] / (T_STEPS * Din); // 4096 (= B*S)

    unsigned short* mem = (unsigned short*)d_ws;                      // M*Din bf16
    unsigned short* Wb  = (unsigned short*)d_ws + (size_t)M * Din;    // Dout*Din bf16

    int mBlocks = M / 2;                      // 2048 (two rows per block)
    int wBlocks = (Dout * Din) / (4 * 256);   // 1024
    prep_kernel<<<mBlocks + wBlocks, 256, 0, stream>>>(x, W, mem, Wb, mBlocks, M, Din);

    int grid = (M / BM) * (Dout / BN);        // 512
    gemm_kernel<<<grid, 256, 0, stream>>>(mem, Wb, bias, out, M, Dout, Din);
}